// Round 5
// baseline (824.552 us; speedup 1.0000x reference)
//
#include <hip/hip_runtime.h>
#include <cfloat>

// Farthest Point Sampling: B=32, N=200000, M=128.
// 8 blocks/batch x 1024 threads, 1 block/CU (LDS-forced), XCD-local batches.
// Per thread: 25 points = 18 in VGPRs (xyz+md, 72 floats) + 7 in LDS float4
// (x,y,z,md). Cross-block argmax via u64 tag slots in the batch's XCD L2;
// intra-block result broadcast via LDS mailbox (no second __syncthreads).
#define B_    32
#define N_    200000
#define M_    128
#define BPB   8                    // blocks per batch
#define T_    1024                 // threads per block
#define PV    18                   // points in VGPRs
#define PL    7                    // points in LDS
#define PT    (PV + PL)            // 25; 8*1024*25 = 204800 >= N
#define CHUNK (T_ * PT)            // 25600 points per block

#define SPIN_CAP (1 << 20)         // safety valve: never hang the container

__global__ __launch_bounds__(T_)
__attribute__((amdgpu_waves_per_eu(4, 4)))   // EXACT 4 waves/EU -> 128-VGPR budget
void fps_kernel(const float* __restrict__ pts, int* __restrict__ out,
                unsigned long long* __restrict__ tags) {
  const int tid = threadIdx.x;
  const int bid = blockIdx.x;
  // XCD-local batches: blocks round-robin XCDs by bid&7 (measured m09), so put
  // all 8 blocks of a batch on one XCD -> slot traffic stays in that L2.
  const int xcd = bid & 7;
  const int sl8 = bid >> 3;                  // 0..31 within this XCD
  const int b   = ((sl8 >> 3) << 3) | xcd;   // batch
  const int c   = sl8 & 7;                   // chunk within batch
  const int wave = tid >> 6;
  const int lane = tid & 63;

  const float* __restrict__ P = pts + (size_t)b * (size_t)(N_ * 3);
  const int base = c * CHUNK + tid;          // this thread's j=0 global index

  // 7 x 1024 x 16B = 114688 B  (> 80 KB -> exactly 1 block/CU)
  __shared__ float4 sP[PL][T_];              // (x,y,z,md), thread-private cols
  __shared__ float  sv[16];
  __shared__ int    si[16];
  __shared__ int    mbTag, mbX, mbY, mbZ;    // intra-block result mailbox

  if (tid == 0) mbTag = 0;

  // ---- one-time load ----
  float vx[PV], vy[PV], vz[PV], md[PV];
  #pragma unroll
  for (int j = 0; j < PV; ++j) {
    int g = base + j * T_;
    if (g < N_) {
      const float* p = P + (size_t)g * 3;
      vx[j] = p[0]; vy[j] = p[1]; vz[j] = p[2];
      md[j] = __builtin_huge_valf();
    } else { vx[j] = vy[j] = vz[j] = 0.f; md[j] = -FLT_MAX; }
  }
  #pragma unroll
  for (int k = 0; k < PL; ++k) {
    int g = base + (PV + k) * T_;
    float4 p4;
    if (g < N_) {
      const float* p = P + (size_t)g * 3;
      p4 = make_float4(p[0], p[1], p[2], __builtin_huge_valf());
    } else {
      p4 = make_float4(0.f, 0.f, 0.f, -FLT_MAX);
    }
    sP[k][tid] = p4;
  }

  float cx = P[0], cy = P[1], cz = P[2];     // initial center = point 0
  if (c == 0 && tid == 0) out[b * M_ + 0] = 0;

  for (int it = 1; it < M_; ++it) {
    // ---- distance + running-min + 4-chain argmax ----
    // No exclusion select needed: the chosen point's distance to itself is
    // exactly 0 (coords pass through bit-exact), min(md,0)=0 never beats any
    // positive min-dist, so the argmax sequence matches the reference.
    float bv[4] = {-FLT_MAX, -FLT_MAX, -FLT_MAX, -FLT_MAX};
    int   bi[4] = {0x7FFFFFFF, 0x7FFFFFFF, 0x7FFFFFFF, 0x7FFFFFFF};

    #pragma unroll
    for (int j = 0; j < PV; ++j) {
      float dx = __fsub_rn(vx[j], cx);
      float dy = __fsub_rn(vy[j], cy);
      float dz = __fsub_rn(vz[j], cz);
      // numpy: ((dx*dx + dy*dy) + dz*dz), rn, no FMA contraction
      float d  = __fadd_rn(__fadd_rn(__fmul_rn(dx, dx), __fmul_rn(dy, dy)),
                           __fmul_rn(dz, dz));
      float m  = fminf(md[j], d);            // np.minimum
      md[j] = m;
      const int q = j & 3;
      bool take = m > bv[q];                 // ascending index: strict >
      bv[q] = take ? m : bv[q];
      bi[q] = take ? (base + j * T_) : bi[q];
    }
    #pragma unroll
    for (int k = 0; k < PL; ++k) {
      const int j = PV + k;
      float4 p = sP[k][tid];
      float dx = __fsub_rn(p.x, cx);
      float dy = __fsub_rn(p.y, cy);
      float dz = __fsub_rn(p.z, cz);
      float d  = __fadd_rn(__fadd_rn(__fmul_rn(dx, dx), __fmul_rn(dy, dy)),
                           __fmul_rn(dz, dz));
      float m  = fminf(p.w, d);
      sP[k][tid].w = m;                      // ds_write_b32 at .w
      const int q = j & 3;
      bool take = m > bv[q];
      bv[q] = take ? m : bv[q];
      bi[q] = take ? (base + j * T_) : bi[q];
    }
    // merge 4 chains (tie -> smaller index = first occurrence)
    float tv = bv[0]; int ti = bi[0];
    #pragma unroll
    for (int q = 1; q < 4; ++q) {
      bool take = (bv[q] > tv) || (bv[q] == tv && bi[q] < ti);
      tv = take ? bv[q] : tv;
      ti = take ? bi[q] : ti;
    }

    // ---- wave reduction (64 lanes) ----
    #pragma unroll
    for (int o = 32; o > 0; o >>= 1) {
      float ov = __shfl_xor(tv, o);
      int   oi = __shfl_xor(ti, o);
      bool take = (ov > tv) || (ov == tv && oi < ti);
      tv = take ? ov : tv;
      ti = take ? oi : ti;
    }
    if (lane == 0) { sv[wave] = tv; si[wave] = ti; }
    __syncthreads();

    if (wave == 0) {
      // cross-wave reduce (16 entries)
      float v = (lane < 16) ? sv[lane] : -FLT_MAX;
      int   i = (lane < 16) ? si[lane] : 0x7FFFFFFF;
      #pragma unroll
      for (int o = 8; o > 0; o >>= 1) {
        float ov = __shfl_xor(v, o);
        int   oi = __shfl_xor(i, o);
        bool take = (ov > v) || (ov == v && oi < i);
        v = take ? ov : v;
        i = take ? oi : i;
      }
      // publish immediately: tag = (valbits<<32)|(idx<<7)|iter
      unsigned long long* grp = tags + ((b << 1) + (it & 1)) * BPB;
      if (lane == 0) {
        unsigned long long tg =
            ((unsigned long long)__float_as_uint(v) << 32) |
            ((unsigned long long)(unsigned)i << 7) | (unsigned)it;
        __hip_atomic_store(grp + c, tg, __ATOMIC_RELEASE, __HIP_MEMORY_SCOPE_AGENT);
      }
      // poll the 8 block candidates (lanes 0..7, XCD-local L2)
      unsigned long long t = 0;
      if (lane < BPB) {
        int sp = 0;
        for (;;) {
          t = __hip_atomic_load(grp + lane, __ATOMIC_ACQUIRE, __HIP_MEMORY_SCOPE_AGENT);
          if ((t & 127ull) == (unsigned long long)(unsigned)it) break;
          if (++sp > SPIN_CAP) break;        // wrong answer >> dead container
          __builtin_amdgcn_s_sleep(1);
        }
      }
      float cv = (lane < BPB) ? __uint_as_float((unsigned)(t >> 32)) : -FLT_MAX;
      int   ci = (lane < BPB) ? (int)((t >> 7) & 0x3FFFF) : 0x7FFFFFFF;
      #pragma unroll
      for (int o = 4; o > 0; o >>= 1) {
        float ov = __shfl_xor(cv, o);
        int   oi = __shfl_xor(ci, o);
        bool take = (ov > cv) || (ov == cv && oi < ci);
        cv = take ? ov : cv;
        ci = take ? oi : ci;
      }
      if (lane == 0) {
        if (c == 0) out[b * M_ + it] = ci;   // fire-and-forget
        const float* pw = P + (size_t)ci * 3; // L2/L3-warm winner coords
        int xb = __float_as_int(pw[0]);
        int yb = __float_as_int(pw[1]);
        int zb = __float_as_int(pw[2]);
        __hip_atomic_store(&mbX, xb, __ATOMIC_RELAXED, __HIP_MEMORY_SCOPE_WORKGROUP);
        __hip_atomic_store(&mbY, yb, __ATOMIC_RELAXED, __HIP_MEMORY_SCOPE_WORKGROUP);
        __hip_atomic_store(&mbZ, zb, __ATOMIC_RELAXED, __HIP_MEMORY_SCOPE_WORKGROUP);
        __hip_atomic_store(&mbTag, it, __ATOMIC_RELEASE, __HIP_MEMORY_SCOPE_WORKGROUP);
      }
    }
    // ---- all waves: spin on LDS mailbox (replaces 2nd __syncthreads) ----
    {
      int sp = 0;
      while (__hip_atomic_load(&mbTag, __ATOMIC_ACQUIRE, __HIP_MEMORY_SCOPE_WORKGROUP) != it) {
        if (++sp > SPIN_CAP) break;
        __builtin_amdgcn_s_sleep(1);
      }
      cx = __int_as_float(__hip_atomic_load(&mbX, __ATOMIC_RELAXED, __HIP_MEMORY_SCOPE_WORKGROUP));
      cy = __int_as_float(__hip_atomic_load(&mbY, __ATOMIC_RELAXED, __HIP_MEMORY_SCOPE_WORKGROUP));
      cz = __int_as_float(__hip_atomic_load(&mbZ, __ATOMIC_RELAXED, __HIP_MEMORY_SCOPE_WORKGROUP));
    }
  }
}

extern "C" void kernel_launch(void* const* d_in, const int* in_sizes, int n_in,
                              void* d_out, int out_size, void* d_ws, size_t ws_size,
                              hipStream_t stream) {
  const float*        pts  = (const float*)d_in[0];
  int*                out  = (int*)d_out;
  unsigned long long* tags = (unsigned long long*)d_ws;

  // zero tag slots each launch (tag 0 never matches it>=1); capture-safe
  hipMemsetAsync(d_ws, 0, (size_t)B_ * 2 * BPB * sizeof(unsigned long long), stream);

  // 114.7 KiB LDS/block -> 1 block/CU; grid == 256 == CU count -> co-resident.
  fps_kernel<<<dim3(B_ * BPB), dim3(T_), 0, stream>>>(pts, out, tags);
}